// Round 3
// baseline (2521.256 us; speedup 1.0000x reference)
//
#include <hip/hip_runtime.h>
#include <hip/hip_bf16.h>

typedef unsigned short u16;
typedef unsigned int   u32;

__device__ __forceinline__ float b2f(u16 u) {
    return __uint_as_float(((u32)u) << 16);
}
__device__ __forceinline__ u16 f2b(float f) {
    __hip_bfloat16 h = __float2bfloat16(f);
    u16 r; __builtin_memcpy(&r, &h, 2); return r;
}
// dtype-adaptive input load / output store (flag: 1 = fp32, 0 = bf16)
__device__ __forceinline__ float ldin(const void* p, size_t i, bool f32) {
    return f32 ? ((const float*)p)[i] : b2f(((const u16*)p)[i]);
}
__device__ __forceinline__ void stout(void* p, size_t i, float v, bool f32) {
    if (f32) ((float*)p)[i] = v; else ((u16*)p)[i] = f2b(v);
}
__device__ __forceinline__ float ldout(const void* p, size_t i, bool f32) {
    return f32 ? ((const float*)p)[i] : b2f(((const u16*)p)[i]);
}

// dot of 32 fp32 (q) with 32 bf16 (global, 64B-aligned)
__device__ __forceinline__ float dot32g(const float* q, const u16* kp) {
    const uint4* k4 = reinterpret_cast<const uint4*>(kp);
    float s = 0.f;
    #pragma unroll
    for (int i = 0; i < 4; ++i) {
        uint4 u = k4[i];
        u32 uu[4] = {u.x, u.y, u.z, u.w};
        #pragma unroll
        for (int q2 = 0; q2 < 4; ++q2) {
            s += q[i*8 + q2*2]     * __uint_as_float(uu[q2] << 16);
            s += q[i*8 + q2*2 + 1] * __uint_as_float(uu[q2] & 0xffff0000u);
        }
    }
    return s;
}
__device__ __forceinline__ float dot32f(const float* q, const float* k) {
    float s = 0.f;
    #pragma unroll
    for (int c = 0; c < 32; ++c) s += q[c] * k[c];
    return s;
}

// ---------------------------------------------------------------------------
// K-1: dtype detector. If x is fp32, its low u16 halves are ~uniform random
// bits -> ~0.4% decode as bf16 NaN patterns. True bf16 N(0,1) data: none.
// ---------------------------------------------------------------------------
__global__ __launch_bounds__(256) void k_detect(const void* __restrict__ xraw, int* __restrict__ flag)
{
    const u16* xu = (const u16*)xraw;
    int t = threadIdx.x;
    int cnt = 0;
    for (int i = t; i < 524288; i += 256) {
        u16 u = xu[i];
        if ((u & 0x7F80u) == 0x7F80u && (u & 0x007Fu) != 0) cnt++;
    }
    __shared__ int red[256];
    red[t] = cnt; __syncthreads();
    for (int st = 128; st > 0; st >>= 1) {
        if (t < st) red[t] += red[t + st];
        __syncthreads();
    }
    if (t == 0) flag[0] = (red[0] > 16) ? 1 : 0;
}

// ---------------------------------------------------------------------------
// K0: pooled offset lines (dX, dY) + regloss.  offsets [2][131][131]
// ---------------------------------------------------------------------------
__global__ __launch_bounds__(256) void k_setup(const void* __restrict__ off,
                                               float* __restrict__ dX, float* __restrict__ dY,
                                               void* __restrict__ out, const int* __restrict__ flag) {
    bool f32 = flag[0] != 0;
    int t = threadIdx.x;
    if (t < 129) {
        for (int ch = 0; ch < 2; ++ch) {
            float s1 = 0.f, s2 = 0.f;
            for (int i = 0; i < 3; ++i)
                for (int j = 0; j < 3; ++j) {
                    s1 += ldin(off, ch*17161 + (t+i)*131 + (64+j), f32);
                    s2 += ldin(off, ch*17161 + (64+i)*131 + (t+j), f32);
                }
            dX[t*2 + ch] = s1 * (1.0f/9.0f);
            dY[t*2 + ch] = s2 * (1.0f/9.0f);
        }
    }
    float s = 0.f;
    for (int idx = t; idx < 17161; idx += 256) {
        float d = ldin(off, idx, f32) - ldin(off, 17161 + idx, f32);
        s += d * d * (1.0f/17161.0f);
    }
    for (int idx = t; idx < 34060; idx += 256) {
        int ch = idx / 17030;
        int rem = idx - ch*17030;
        int r = rem / 131, c = rem - r*131;
        float a = ldin(off, ch*17161 + r*131 + c, f32);
        float b = ldin(off, ch*17161 + (r+1)*131 + c, f32);
        float d = a - b;
        s += d * d * (1.0f/34060.0f);
    }
    __shared__ float red[256];
    red[t] = s; __syncthreads();
    for (int st = 128; st > 0; st >>= 1) {
        if (t < st) red[t] += red[t + st];
        __syncthreads();
    }
    if (t == 0) {
        float v = red[0];
        if (!(v == v)) v = -299.f;
        stout(out, (size_t)16777216, v, f32);
    }
}

// ---------------------------------------------------------------------------
// K1: projections.  x [B][256][HW]; W* [O][256] (dtype per flag).
// pqx/pkx bf16 [B][HW][32]; pvx bf16 [B][HW][256] (pixel-major).
// grid (128 pixel-tiles of 512, 10 o-tiles of 32), block 256.
// ---------------------------------------------------------------------------
__global__ __launch_bounds__(256) void k_proj(const void* __restrict__ xraw,
    const void* Wq, const void* bq, const void* Wk, const void* bk,
    const void* Wv, const void* bv,
    u16* __restrict__ pqx, u16* __restrict__ pkx, u16* __restrict__ pvx,
    const int* __restrict__ flag)
{
    bool f32 = flag[0] != 0;
    int t  = threadIdx.x;
    int ot = blockIdx.y;
    int gp0 = blockIdx.x * 512;
    int b   = gp0 >> 14;
    int hw0 = gp0 & 16383;
    const void* Wm; const void* bias; int orow;
    if (ot == 0)      { Wm = Wq; bias = bq; orow = 0; }
    else if (ot == 1) { Wm = Wk; bias = bk; orow = 0; }
    else              { Wm = Wv; bias = bv; orow = (ot - 2) * 32; }

    __shared__ u16  xl[32 * 512];
    __shared__ float wl[32][33];
    float acc0[32], acc1[32];
    #pragma unroll
    for (int o = 0; o < 32; ++o) { acc0[o] = 0.f; acc1[o] = 0.f; }

    for (int ck = 0; ck < 8; ++ck) {
        int c0 = ck * 32;
        if (f32) {
            const float* xf = (const float*)xraw;
            for (int i = 0; i < 64; ++i) {
                int idx = i * 256 + t;
                int cc = idx >> 9, px = idx & 511;
                xl[idx] = f2b(xf[(size_t)(b*256 + c0 + cc) * 16384 + hw0 + px]);
            }
        } else {
            const u16* xu = (const u16*)xraw;
            for (int i = 0; i < 64; ++i) {
                int idx = i * 256 + t;
                int cc = idx >> 9, px = idx & 511;
                xl[idx] = xu[(size_t)(b*256 + c0 + cc) * 16384 + hw0 + px];
            }
        }
        #pragma unroll
        for (int i = 0; i < 4; ++i) {
            int idx = i * 256 + t;
            int o = idx >> 5, c = idx & 31;
            wl[o][c] = ldin(Wm, (size_t)(orow + o) * 256 + c0 + c, f32);
        }
        __syncthreads();
        #pragma unroll
        for (int cc = 0; cc < 32; ++cc) {
            float xv0 = b2f(xl[cc*512 + t]);
            float xv1 = b2f(xl[cc*512 + 256 + t]);
            #pragma unroll
            for (int o = 0; o < 32; ++o) {
                float wv = wl[o][cc];
                acc0[o] += wv * xv0;
                acc1[o] += wv * xv1;
            }
        }
        __syncthreads();
    }
    int p0 = hw0 + t, p1 = hw0 + 256 + t;
    u32 w0[16], w1[16];
    #pragma unroll
    for (int o = 0; o < 16; ++o) {
        float b0 = ldin(bias, orow + 2*o, f32), b1 = ldin(bias, orow + 2*o + 1, f32);
        w0[o] = (u32)f2b(acc0[2*o] + b0) | ((u32)f2b(acc0[2*o+1] + b1) << 16);
        w1[o] = (u32)f2b(acc1[2*o] + b0) | ((u32)f2b(acc1[2*o+1] + b1) << 16);
    }
    u16* d0; u16* d1;
    if (ot == 0)      { d0 = pqx + ((size_t)b*16384 + p0)*32; d1 = pqx + ((size_t)b*16384 + p1)*32; }
    else if (ot == 1) { d0 = pkx + ((size_t)b*16384 + p0)*32; d1 = pkx + ((size_t)b*16384 + p1)*32; }
    else              { d0 = pvx + ((size_t)b*16384 + p0)*256 + orow; d1 = pvx + ((size_t)b*16384 + p1)*256 + orow; }
    uint4* q0 = reinterpret_cast<uint4*>(d0);
    uint4* q1 = reinterpret_cast<uint4*>(d1);
    #pragma unroll
    for (int i = 0; i < 4; ++i) {
        q0[i] = make_uint4(w0[4*i], w0[4*i+1], w0[4*i+2], w0[4*i+3]);
        q1[i] = make_uint4(w1[4*i], w1[4*i+1], w1[4*i+2], w1[4*i+3]);
    }
}

// ---------------------------------------------------------------------------
// K2: deformed bilinear sampling for batch 0 (all-internal bf16).
// grid 32768 (variant*16384 + pt), block 320 (32 q + 32 k + 256 v channels).
// variant0 (col lines): pt = w*128+h -> qdH/kdH bf16 [W][H][32], vdH bf16 [W][H][256]
// variant1 (row lines): pt = h*128+w -> qdW/kdW bf16 [H][W][32], vdW bf16 [H][W][256]
// ---------------------------------------------------------------------------
__global__ __launch_bounds__(320) void k_sample(
    const u16* __restrict__ pqx0, const u16* __restrict__ pkx0, const u16* __restrict__ pvx0,
    const float* __restrict__ dX, const float* __restrict__ dY,
    u16* __restrict__ qdH, u16* __restrict__ kdH, u16* __restrict__ vdH,
    u16* __restrict__ qdW, u16* __restrict__ kdW, u16* __restrict__ vdW)
{
    int bid = blockIdx.x;
    int variant = bid >> 14;
    int pt = bid & 16383;
    int t = threadIdx.x;
    int w, h;
    float xn, yn;
    if (variant == 0) {
        w = pt >> 7; h = pt & 127;
        xn = (-1.0f + (float)w     * (2.0f/128.0f)) + dX[(h+1)*2 + 0];
        yn = (-1.0f + (float)(h+1) * (2.0f/128.0f)) + dX[(h+1)*2 + 1];
    } else {
        h = pt >> 7; w = pt & 127;
        xn = (-1.0f + (float)(w+1) * (2.0f/128.0f)) + dY[(w+1)*2 + 0];
        yn = (-1.0f + (float)h     * (2.0f/128.0f)) + dY[(w+1)*2 + 1];
    }
    float fx = (xn + 1.0f) * 0.5f * 127.0f;
    float fy = (yn + 1.0f) * 0.5f * 127.0f;
    float x0f = floorf(fx), y0f = floorf(fy);
    float wx = fx - x0f, wy = fy - y0f;

    float wt[4]; int xi[4], yi[4]; bool vd[4];
    {
        float xs[2]  = { x0f, x0f + 1.0f };
        float ys[2]  = { y0f, y0f + 1.0f };
        float wxs[2] = { 1.0f - wx, wx };
        float wys[2] = { 1.0f - wy, wy };
        #pragma unroll
        for (int jy = 0; jy < 2; ++jy)
            #pragma unroll
            for (int jx = 0; jx < 2; ++jx) {
                int k = jy*2 + jx;
                vd[k] = (xs[jx] >= 0.f) && (xs[jx] < 128.f) && (ys[jy] >= 0.f) && (ys[jy] < 128.f);
                wt[k] = wxs[jx] * wys[jy];
                xi[k] = (int)fminf(fmaxf(xs[jx], 0.f), 127.f);
                yi[k] = (int)fminf(fmaxf(ys[jy], 0.f), 127.f);
            }
    }
    float val = 0.f;
    if (t < 32) {
        int c = t;
        #pragma unroll
        for (int k = 0; k < 4; ++k)
            if (vd[k]) val += wt[k] * b2f(pqx0[(size_t)(yi[k]*128 + xi[k])*32 + c]);
        if (variant == 0) qdH[(size_t)pt*32 + c] = f2b(val);
        else              qdW[(size_t)pt*32 + c] = f2b(val);
    } else if (t < 64) {
        int c = t - 32;
        #pragma unroll
        for (int k = 0; k < 4; ++k)
            if (vd[k]) val += wt[k] * b2f(pkx0[(size_t)(yi[k]*128 + xi[k])*32 + c]);
        if (variant == 0) kdH[(size_t)pt*32 + c] = f2b(val);
        else              kdW[(size_t)pt*32 + c] = f2b(val);
    } else {
        int c = t - 64;
        #pragma unroll
        for (int k = 0; k < 4; ++k)
            if (vd[k]) val += wt[k] * b2f(pvx0[(size_t)(yi[k]*128 + xi[k])*256 + c]);
        if (variant == 0) vdH[(size_t)pt*256 + c] = f2b(val);
        else              vdW[(size_t)pt*256 + c] = f2b(val);
    }
}

// ---------------------------------------------------------------------------
// K3: fused scores + joint softmax.  block per (b,h), 256 threads.
// attbH[b][h][w][jH] bf16, attbW[b][h][w][jW] bf16 (normalized probs).
// ---------------------------------------------------------------------------
__global__ __launch_bounds__(256) void k_fused(
    const u16* __restrict__ pqx, const u16* __restrict__ pkx,
    const u16* __restrict__ qdH, const u16* __restrict__ kdH,
    const u16* __restrict__ qdW, const u16* __restrict__ kdW,
    u16* __restrict__ attbH, u16* __restrict__ attbW)
{
    int b = blockIdx.x >> 7, h = blockIdx.x & 127;
    int t = threadIdx.x;
    __shared__ float qr[128*33];   // row-line q  [w][c]
    __shared__ float kr[128*33];   // row-line k  [j][c]
    __shared__ float qc[128*33];   // col-line q  [w][c]
    __shared__ float mh[256], zh[256];
    __shared__ float Mw[128], Iw[128];

    {
        const u16* qrsrc = (b == 0) ? (qdW + (size_t)h*4096) : (pqx + ((size_t)b*16384 + h*128)*32);
        const u16* krsrc = (b == 0) ? (kdW + (size_t)h*4096) : (pkx + ((size_t)b*16384 + h*128)*32);
        for (int i = t; i < 4096; i += 256) {
            int w = i >> 5, c = i & 31;
            qr[w*33 + c] = b2f(qrsrc[i]);
            kr[w*33 + c] = b2f(krsrc[i]);
        }
        if (b == 0) {
            for (int i = t; i < 4096; i += 256) {
                int w = i >> 5, c = i & 31;
                qc[w*33 + c] = b2f(qdH[((size_t)w*128 + h)*32 + c]);
            }
        } else {
            for (int i = t; i < 4096; i += 256) {
                int w = i >> 5, c = i & 31;
                qc[w*33 + c] = b2f(pqx[((size_t)b*16384 + h*128)*32 + i]);
            }
        }
    }
    __syncthreads();

    // ---- pass A: online max/sum.  lane = w; kind0 = col scores, kind1 = row.
    int w = t & 127, kind = t >> 7;
    float qreg[32];
    {
        const float* qsrc = kind ? (qr + w*33) : (qc + w*33);
        #pragma unroll
        for (int c = 0; c < 32; ++c) qreg[c] = qsrc[c];
    }
    float m = -INFINITY, Z = 0.f;
    if (kind == 0) {
        const u16* ksrc; size_t jstride;
        if (b == 0) { ksrc = kdH + (size_t)w*4096;                 jstride = 32;   }
        else        { ksrc = pkx + ((size_t)b*16384 + w)*32;       jstride = 4096; }
        for (int j = 0; j < 128; ++j) {
            if (j == h) continue;
            float s = dot32g(qreg, ksrc + (size_t)j * jstride);
            float mn = fmaxf(m, s);
            Z = Z * __expf(m - mn) + __expf(s - mn);
            m = mn;
        }
    } else {
        for (int j = 0; j < 128; ++j) {
            float s = dot32f(qreg, kr + j*33);
            float mn = fmaxf(m, s);
            Z = Z * __expf(m - mn) + __expf(s - mn);
            m = mn;
        }
    }
    mh[t] = m; zh[t] = Z;
    __syncthreads();
    if (t < 128) {
        float m0 = mh[t], m1 = mh[128 + t];
        float M = fmaxf(m0, m1);
        float Zt = zh[t] * __expf(m0 - M) + zh[128 + t] * __expf(m1 - M);
        Mw[t] = M; Iw[t] = 1.0f / Zt;
    }
    __syncthreads();

    // ---- pass B: recompute scores, write normalized bf16 probs. lane = j.
    int j = t & 127;
    if (kind == 0) {
        const u16* ksrc; size_t wstride;
        if (b == 0) { ksrc = kdH + (size_t)j*32;                  wstride = 4096; }
        else        { ksrc = pkx + ((size_t)b*16384 + j*128)*32;  wstride = 32;   }
        u16* dst = attbH + ((size_t)(b*128 + h)*128)*128 + j;
        if (j == h) {
            for (int w2 = 0; w2 < 128; ++w2) dst[(size_t)w2*128] = 0;
        } else {
            for (int w2 = 0; w2 < 128; ++w2) {
                float s = dot32g(qc + w2*33, ksrc + (size_t)w2 * wstride);
                float p = __expf(s - Mw[w2]) * Iw[w2];
                dst[(size_t)w2*128] = f2b(p);
            }
        }
    } else {
        u16* dst = attbW + ((size_t)(b*128 + h)*128)*128 + j;
        for (int w2 = 0; w2 < 128; ++w2) {
            float s = dot32f(qr + w2*33, kr + j*33);
            float p = __expf(s - Mw[w2]) * Iw[w2];
            dst[(size_t)w2*128] = f2b(p);
        }
    }
}

// ---------------------------------------------------------------------------
// K4: column aggregation -> outH (dtype per flag) into d_out.
// out[b][c][k][w] = sum_h v[c,h,w] * attbH[b,k,w,h].  block (b,w), thread = c.
// ---------------------------------------------------------------------------
__global__ __launch_bounds__(256) void k_outcol(const u16* __restrict__ pvx, const u16* __restrict__ vdH,
    const u16* __restrict__ attbH, void* __restrict__ out, const int* __restrict__ flag)
{
    bool f32 = flag[0] != 0;
    int b = blockIdx.x >> 7, w = blockIdx.x & 127;
    int t = threadIdx.x;
    __shared__ float al[128*128];   // [h_key][k_query]
    {
        int k = t & 127;
        int hbase = (t >> 7) * 64;
        for (int i = 0; i < 8; ++i) {
            int hh = hbase + i*8;
            size_t g = ((size_t)(b*128 + k)*128 + w)*128 + hh;
            uint4 u = *reinterpret_cast<const uint4*>(attbH + g);
            u32 uu[4] = { u.x, u.y, u.z, u.w };
            #pragma unroll
            for (int q = 0; q < 4; ++q) {
                al[(hh + 2*q    )*128 + k] = __uint_as_float(uu[q] << 16);
                al[(hh + 2*q + 1)*128 + k] = __uint_as_float(uu[q] & 0xffff0000u);
            }
        }
    }
    int c = t;
    const u16* vsrc; size_t hstride;
    if (b == 0) { vsrc = vdH + (size_t)w*128*256 + c; hstride = 256;   }
    else        { vsrc = pvx + ((size_t)b*16384 + w)*256 + c; hstride = 32768; }
    u32 vp[64];
    for (int i = 0; i < 64; ++i) {
        u32 lo = vsrc[(size_t)(2*i)   * hstride];
        u32 hi = vsrc[(size_t)(2*i+1) * hstride];
        vp[i] = lo | (hi << 16);
    }
    __syncthreads();
    for (int kc = 0; kc < 8; ++kc) {
        int k0 = kc * 16;
        float acc[16];
        #pragma unroll
        for (int kk = 0; kk < 16; ++kk) acc[kk] = 0.f;
        for (int hp = 0; hp < 64; ++hp) {
            u32 p = vp[hp];
            float v0 = __uint_as_float(p << 16);
            float v1 = __uint_as_float(p & 0xffff0000u);
            const float4* a0 = reinterpret_cast<const float4*>(&al[(2*hp)*128 + k0]);
            const float4* a1 = reinterpret_cast<const float4*>(&al[(2*hp+1)*128 + k0]);
            #pragma unroll
            for (int q = 0; q < 4; ++q) {
                float4 x0 = a0[q], x1 = a1[q];
                acc[q*4+0] += v0*x0.x; acc[q*4+1] += v0*x0.y; acc[q*4+2] += v0*x0.z; acc[q*4+3] += v0*x0.w;
                acc[q*4+0] += v1*x1.x; acc[q*4+1] += v1*x1.y; acc[q*4+2] += v1*x1.z; acc[q*4+3] += v1*x1.w;
            }
        }
        #pragma unroll
        for (int kk = 0; kk < 16; ++kk)
            stout(out, ((size_t)(b*256 + c)*128 + (k0 + kk))*128 + w, acc[kk], f32);
    }
}

// ---------------------------------------------------------------------------
// K5: row aggregation + epilogue (dtype per flag for x/gamma/out).
// out[b][c][h][k] = gamma*(outH + sum_j v[c,h,j]*attbW[b,h,k,j]) + x
// block (b,h), thread = c.
// ---------------------------------------------------------------------------
__global__ __launch_bounds__(256) void k_outrow(const u16* __restrict__ pvx, const u16* __restrict__ vdW,
    const u16* __restrict__ attbW, const void* __restrict__ xraw,
    const void* __restrict__ gamma, void* __restrict__ out, const int* __restrict__ flag)
{
    bool f32 = flag[0] != 0;
    int b = blockIdx.x >> 7, h = blockIdx.x & 127;
    int t = threadIdx.x;
    __shared__ float al[128*128];   // [j_key][k_query]
    {
        int k = t & 127;
        int jbase = (t >> 7) * 64;
        for (int i = 0; i < 8; ++i) {
            int jj = jbase + i*8;
            size_t g = ((size_t)(b*128 + h)*128 + k)*128 + jj;
            uint4 u = *reinterpret_cast<const uint4*>(attbW + g);
            u32 uu[4] = { u.x, u.y, u.z, u.w };
            #pragma unroll
            for (int q = 0; q < 4; ++q) {
                al[(jj + 2*q    )*128 + k] = __uint_as_float(uu[q] << 16);
                al[(jj + 2*q + 1)*128 + k] = __uint_as_float(uu[q] & 0xffff0000u);
            }
        }
    }
    int c = t;
    const u16* vsrc = (b == 0) ? (vdW + (size_t)h*128*256 + c)
                               : (pvx + ((size_t)b*16384 + h*128)*256 + c);
    u32 vp[64];
    for (int i = 0; i < 64; ++i) {
        u32 lo = vsrc[(size_t)(2*i)   * 256];
        u32 hi = vsrc[(size_t)(2*i+1) * 256];
        vp[i] = lo | (hi << 16);
    }
    float gm = ldin(gamma, 0, f32);
    __syncthreads();
    for (int kc = 0; kc < 8; ++kc) {
        int k0 = kc * 16;
        float acc[16];
        #pragma unroll
        for (int kk = 0; kk < 16; ++kk) acc[kk] = 0.f;
        for (int jp = 0; jp < 64; ++jp) {
            u32 p = vp[jp];
            float v0 = __uint_as_float(p << 16);
            float v1 = __uint_as_float(p & 0xffff0000u);
            const float4* a0 = reinterpret_cast<const float4*>(&al[(2*jp)*128 + k0]);
            const float4* a1 = reinterpret_cast<const float4*>(&al[(2*jp+1)*128 + k0]);
            #pragma unroll
            for (int q = 0; q < 4; ++q) {
                float4 x0 = a0[q], x1 = a1[q];
                acc[q*4+0] += v0*x0.x; acc[q*4+1] += v0*x0.y; acc[q*4+2] += v0*x0.z; acc[q*4+3] += v0*x0.w;
                acc[q*4+0] += v1*x1.x; acc[q*4+1] += v1*x1.y; acc[q*4+2] += v1*x1.z; acc[q*4+3] += v1*x1.w;
            }
        }
        size_t base = ((size_t)(b*256 + c)*128 + h)*128 + k0;
        #pragma unroll
        for (int kk = 0; kk < 16; ++kk) {
            size_t idx = base + kk;
            float hst = ldout(out, idx, f32);       // outH staged by k_outcol
            float xv  = ldin(xraw, idx, f32);
            float v = gm * (hst + acc[kk]) + xv;
            if (!(v == v)) v = -299.f;              // NaN-proof diagnostic
            stout(out, idx, v, f32);
        }
    }
}

// ---------------------------------------------------------------------------
extern "C" void kernel_launch(void* const* d_in, const int* in_sizes, int n_in,
                              void* d_out, int out_size, void* d_ws, size_t ws_size,
                              hipStream_t stream)
{
    const void* x     = d_in[0];
    const void* Wq    = d_in[1];
    const void* bq    = d_in[2];
    const void* Wk    = d_in[3];
    const void* bk    = d_in[4];
    const void* Wv    = d_in[5];
    const void* bv    = d_in[6];
    const void* gamma = d_in[7];
    const void* off   = d_in[8];

    char* ws = (char*)d_ws;
    size_t o = 0;
    auto alloc = [&](size_t bytes) { size_t r = o; o += (bytes + 255) & ~(size_t)255; return r; };
    int*   flag = (int*)(ws + alloc(256));
    float* dX   = (float*)(ws + alloc(129*2*4));
    float* dY   = (float*)(ws + alloc(129*2*4));
    u16*   pqx  = (u16*)(ws + alloc((size_t)4*16384*32*2));    // [B][HW][32]
    u16*   pkx  = (u16*)(ws + alloc((size_t)4*16384*32*2));
    u16*   pvx  = (u16*)(ws + alloc((size_t)4*16384*256*2));   // [B][HW][256]
    u16*   qdH  = (u16*)(ws + alloc((size_t)16384*32*2));      // [W][H][32]
    u16*   kdH  = (u16*)(ws + alloc((size_t)16384*32*2));
    u16*   qdW  = (u16*)(ws + alloc((size_t)16384*32*2));      // [H][W][32]
    u16*   kdW  = (u16*)(ws + alloc((size_t)16384*32*2));
    u16*   vdH  = (u16*)(ws + alloc((size_t)16384*256*2));     // [W][H][256]
    u16*   vdW  = (u16*)(ws + alloc((size_t)16384*256*2));     // [H][W][256]
    u16*   attbH= (u16*)(ws + alloc((size_t)4*128*128*128*2)); // [B][H][W][128]
    u16*   attbW= (u16*)(ws + alloc((size_t)4*128*128*128*2)); // [B][H][W][128]

    k_detect <<<1, 256, 0, stream>>>(x, flag);
    k_setup  <<<1, 256, 0, stream>>>(off, dX, dY, d_out, flag);
    k_proj   <<<dim3(128, 10), 256, 0, stream>>>(x, Wq, bq, Wk, bk, Wv, bv, pqx, pkx, pvx, flag);
    k_sample <<<32768, 320, 0, stream>>>(pqx, pkx, pvx, dX, dY, qdH, kdH, vdH, qdW, kdW, vdW);
    k_fused  <<<512, 256, 0, stream>>>(pqx, pkx, qdH, kdH, qdW, kdW, attbH, attbW);
    k_outcol <<<512, 256, 0, stream>>>(pvx, vdH, attbH, d_out, flag);
    k_outrow <<<512, 256, 0, stream>>>(pvx, vdW, attbW, x, gamma, d_out, flag);
    (void)in_sizes; (void)n_in; (void)out_size; (void)ws_size;
}

// Round 4
// 1302.383 us; speedup vs baseline: 1.9359x; 1.9359x over previous
//
#include <hip/hip_runtime.h>
#include <hip/hip_bf16.h>

typedef unsigned short u16;
typedef unsigned int   u32;
typedef short bf16x8 __attribute__((ext_vector_type(8)));
typedef float f32x4  __attribute__((ext_vector_type(4)));

__device__ __forceinline__ float b2f(u16 u) {
    return __uint_as_float(((u32)u) << 16);
}
__device__ __forceinline__ u16 f2b(float f) {
    __hip_bfloat16 h = __float2bfloat16(f);
    u16 r; __builtin_memcpy(&r, &h, 2); return r;
}
// dtype-adaptive input load / output store (flag: 1 = fp32, 0 = bf16)
__device__ __forceinline__ float ldin(const void* p, size_t i, bool f32) {
    return f32 ? ((const float*)p)[i] : b2f(((const u16*)p)[i]);
}
__device__ __forceinline__ void stout(void* p, size_t i, float v, bool f32) {
    if (f32) ((float*)p)[i] = v; else ((u16*)p)[i] = f2b(v);
}
__device__ __forceinline__ float ldout(const void* p, size_t i, bool f32) {
    return f32 ? ((const float*)p)[i] : b2f(((const u16*)p)[i]);
}

// dot of 32 fp32 (q) with 32 bf16 (global, 64B-aligned)
__device__ __forceinline__ float dot32g(const float* q, const u16* kp) {
    const uint4* k4 = reinterpret_cast<const uint4*>(kp);
    float s = 0.f;
    #pragma unroll
    for (int i = 0; i < 4; ++i) {
        uint4 u = k4[i];
        u32 uu[4] = {u.x, u.y, u.z, u.w};
        #pragma unroll
        for (int q2 = 0; q2 < 4; ++q2) {
            s += q[i*8 + q2*2]     * __uint_as_float(uu[q2] << 16);
            s += q[i*8 + q2*2 + 1] * __uint_as_float(uu[q2] & 0xffff0000u);
        }
    }
    return s;
}
__device__ __forceinline__ float dot32f(const float* q, const float* k) {
    float s = 0.f;
    #pragma unroll
    for (int c = 0; c < 32; ++c) s += q[c] * k[c];
    return s;
}

// ---------------------------------------------------------------------------
// K-1: dtype detector (fp32 low halves ~ uniform bits -> bf16-NaN patterns).
// ---------------------------------------------------------------------------
__global__ __launch_bounds__(256) void k_detect(const void* __restrict__ xraw, int* __restrict__ flag)
{
    const uint4* xv = (const uint4*)xraw;
    int t = threadIdx.x;
    int cnt = 0;
    for (int i = t; i < 8192; i += 256) {   // 64K u16 = 128 KB sample
        uint4 u = xv[i];
        u32 uu[4] = {u.x, u.y, u.z, u.w};
        #pragma unroll
        for (int q = 0; q < 4; ++q) {
            u16 a = (u16)(uu[q] & 0xffff), b = (u16)(uu[q] >> 16);
            if ((a & 0x7F80u) == 0x7F80u && (a & 0x007Fu) != 0) cnt++;
            if ((b & 0x7F80u) == 0x7F80u && (b & 0x007Fu) != 0) cnt++;
        }
    }
    __shared__ int red[256];
    red[t] = cnt; __syncthreads();
    for (int st = 128; st > 0; st >>= 1) {
        if (t < st) red[t] += red[t + st];
        __syncthreads();
    }
    if (t == 0) flag[0] = (red[0] > 16) ? 1 : 0;
}

// ---------------------------------------------------------------------------
// K0: pooled offset lines (dX, dY) + regloss.  offsets [2][131][131]
// ---------------------------------------------------------------------------
__global__ __launch_bounds__(256) void k_setup(const void* __restrict__ off,
                                               float* __restrict__ dX, float* __restrict__ dY,
                                               void* __restrict__ out, const int* __restrict__ flag) {
    bool f32 = flag[0] != 0;
    int t = threadIdx.x;
    if (t < 129) {
        for (int ch = 0; ch < 2; ++ch) {
            float s1 = 0.f, s2 = 0.f;
            for (int i = 0; i < 3; ++i)
                for (int j = 0; j < 3; ++j) {
                    s1 += ldin(off, ch*17161 + (t+i)*131 + (64+j), f32);
                    s2 += ldin(off, ch*17161 + (64+i)*131 + (t+j), f32);
                }
            dX[t*2 + ch] = s1 * (1.0f/9.0f);
            dY[t*2 + ch] = s2 * (1.0f/9.0f);
        }
    }
    float s = 0.f;
    for (int idx = t; idx < 17161; idx += 256) {
        float d = ldin(off, idx, f32) - ldin(off, 17161 + idx, f32);
        s += d * d * (1.0f/17161.0f);
    }
    for (int idx = t; idx < 34060; idx += 256) {
        int ch = idx / 17030;
        int rem = idx - ch*17030;
        int r = rem / 131, c = rem - r*131;
        float a = ldin(off, ch*17161 + r*131 + c, f32);
        float b = ldin(off, ch*17161 + (r+1)*131 + c, f32);
        float d = a - b;
        s += d * d * (1.0f/34060.0f);
    }
    __shared__ float red[256];
    red[t] = s; __syncthreads();
    for (int st = 128; st > 0; st >>= 1) {
        if (t < st) red[t] += red[t + st];
        __syncthreads();
    }
    if (t == 0) {
        float v = red[0];
        if (!(v == v)) v = -299.f;
        stout(out, (size_t)16777216, v, f32);
    }
}

// ---------------------------------------------------------------------------
// K1: MFMA projections.  GEMM W[320,256] x X[256, B*HW].
// W split into bf16 hi+lo (keeps ~fp32 weight precision, 2 chained MFMAs).
// Outputs: pqk bf16 [B][HW][64] (q=0..31,k=32..63); pvx bf16 [B][HW][256].
// grid dim3(5, 512): blockIdx.x = o-tile (64 o), blockIdx.y = px-tile (128 px).
// ---------------------------------------------------------------------------
__global__ __launch_bounds__(256) void k_proj_mfma(
    const void* __restrict__ xraw,
    const void* Wq, const void* bq, const void* Wk, const void* bk,
    const void* Wv, const void* bv,
    u16* __restrict__ pqk, u16* __restrict__ pvx, const int* __restrict__ flag)
{
    bool f32 = flag[0] != 0;
    int t = threadIdx.x;
    int ot = blockIdx.x;                 // 0..4
    int gp = blockIdx.y * 128;           // global pixel base over B*HW
    int b  = gp >> 14;
    int p0 = gp & 16383;
    int o_base = ot * 64;                // combined o space: q[0,32) k[32,64) v[64,320)

    __shared__ __align__(16) u16 WH [64*32];
    __shared__ __align__(16) u16 WLo[64*32];
    __shared__ __align__(16) u16 XL [128*32];

    f32x4 acc[4][2];
    #pragma unroll
    for (int i = 0; i < 4; ++i)
        #pragma unroll
        for (int j = 0; j < 2; ++j) acc[i][j] = (f32x4){0.f, 0.f, 0.f, 0.f};

    int wid = t >> 6, lane = t & 63;
    int quad = lane >> 4, n = lane & 15;

    for (int kc = 0; kc < 8; ++kc) {
        int c0 = kc * 32;
        // stage W hi/lo: 64 o x 32 k
        #pragma unroll
        for (int i = 0; i < 8; ++i) {
            int idx = i*256 + t;
            int o = idx >> 5, k = idx & 31;
            int og = o_base + o;
            const void* wsrc; int row;
            if (og < 32)      { wsrc = Wq; row = og; }
            else if (og < 64) { wsrc = Wk; row = og - 32; }
            else              { wsrc = Wv; row = og - 64; }
            float wv = ldin(wsrc, (size_t)row*256 + c0 + k, f32);
            u16 hi = f2b(wv);
            WH [o*32 + k] = hi;
            WLo[o*32 + k] = f2b(wv - b2f(hi));
        }
        // stage X: 128 px x 32 k (pack 2 consecutive k from 2 c-rows)
        #pragma unroll
        for (int i = 0; i < 8; ++i) {
            int idx = i*256 + t;          // 0..2047
            int cp = idx >> 7;            // k-pair 0..15
            int px = idx & 127;
            size_t base = ((size_t)(b*256 + c0 + 2*cp))*16384 + p0 + px;
            u16 lo16, hi16;
            if (f32) {
                const float* xf = (const float*)xraw;
                lo16 = f2b(xf[base]); hi16 = f2b(xf[base + 16384]);
            } else {
                const u16* xu = (const u16*)xraw;
                lo16 = xu[base]; hi16 = xu[base + 16384];
            }
            *reinterpret_cast<u32*>(&XL[px*32 + 2*cp]) = (u32)lo16 | ((u32)hi16 << 16);
        }
        __syncthreads();
        bf16x8 bf0 = *reinterpret_cast<const bf16x8*>(&XL[(wid*32 +      n)*32 + quad*8]);
        bf16x8 bf1 = *reinterpret_cast<const bf16x8*>(&XL[(wid*32 + 16 + n)*32 + quad*8]);
        #pragma unroll
        for (int ot2 = 0; ot2 < 4; ++ot2) {
            bf16x8 ah = *reinterpret_cast<const bf16x8*>(&WH [(ot2*16 + n)*32 + quad*8]);
            bf16x8 al = *reinterpret_cast<const bf16x8*>(&WLo[(ot2*16 + n)*32 + quad*8]);
            acc[ot2][0] = __builtin_amdgcn_mfma_f32_16x16x32_bf16(ah, bf0, acc[ot2][0], 0, 0, 0);
            acc[ot2][0] = __builtin_amdgcn_mfma_f32_16x16x32_bf16(al, bf0, acc[ot2][0], 0, 0, 0);
            acc[ot2][1] = __builtin_amdgcn_mfma_f32_16x16x32_bf16(ah, bf1, acc[ot2][1], 0, 0, 0);
            acc[ot2][1] = __builtin_amdgcn_mfma_f32_16x16x32_bf16(al, bf1, acc[ot2][1], 0, 0, 0);
        }
        __syncthreads();
    }
    // epilogue: D[row=quad*4+reg][col=n]; 4 consecutive o per lane per frag
    #pragma unroll
    for (int ot2 = 0; ot2 < 4; ++ot2) {
        int o_l = ot2*16 + quad*4;
        int og  = o_base + o_l;
        const void* bsrc; int boff;
        if (og < 32)      { bsrc = bq; boff = og; }
        else if (og < 64) { bsrc = bk; boff = og - 32; }
        else              { bsrc = bv; boff = og - 64; }
        float b0 = ldin(bsrc, boff,   f32), b1 = ldin(bsrc, boff+1, f32);
        float b2 = ldin(bsrc, boff+2, f32), b3 = ldin(bsrc, boff+3, f32);
        #pragma unroll
        for (int pt = 0; pt < 2; ++pt) {
            f32x4 a = acc[ot2][pt];
            int px = p0 + wid*32 + pt*16 + n;
            u32 w0 = (u32)f2b(a[0] + b0) | ((u32)f2b(a[1] + b1) << 16);
            u32 w1 = (u32)f2b(a[2] + b2) | ((u32)f2b(a[3] + b3) << 16);
            u16* dst;
            if (ot == 0) dst = pqk + ((size_t)(b*16384 + px))*64  + o_l;
            else         dst = pvx + ((size_t)(b*16384 + px))*256 + (o_base - 64 + o_l);
            *reinterpret_cast<uint2*>(dst) = make_uint2(w0, w1);
        }
    }
}

// ---------------------------------------------------------------------------
// K1b: transpose k-half of pqk into col-major pkc[B][W][H][32]  (b>=1 only;
// b=0 slice is written by k_sample).  grid 192, block 256.
// ---------------------------------------------------------------------------
__global__ __launch_bounds__(256) void k_transqk(const u16* __restrict__ pqk, u16* __restrict__ pkc)
{
    int pg = 16384 + blockIdx.x*256 + threadIdx.x;
    int b = pg >> 14, hw = pg & 16383, h = hw >> 7, w = hw & 127;
    const uint4* src = reinterpret_cast<const uint4*>(pqk + (size_t)pg*64 + 32);
    uint4* dst = reinterpret_cast<uint4*>(pkc + (((size_t)(b*128 + w))*128 + h)*32);
    #pragma unroll
    for (int i = 0; i < 4; ++i) dst[i] = src[i];
}

// ---------------------------------------------------------------------------
// K1c: transpose pvx into col-major pvc[B][W][H][256]  (b>=1 only).
// grid 6144, block 256 (8 px rows x 32 c-groups).
// ---------------------------------------------------------------------------
__global__ __launch_bounds__(256) void k_transv(const u16* __restrict__ pvx, u16* __restrict__ pvc)
{
    int t = threadIdx.x;
    int p = 16384 + blockIdx.x*8 + (t >> 5);
    int c = (t & 31)*8;
    int b = p >> 14, hw = p & 16383, h = hw >> 7, w = hw & 127;
    *reinterpret_cast<uint4*>(pvc + (((size_t)(b*128 + w))*128 + h)*256 + c) =
        *reinterpret_cast<const uint4*>(pvx + (size_t)p*256 + c);
}

// ---------------------------------------------------------------------------
// K2: deformed bilinear sampling for batch 0.
// grid 32768 (variant*16384 + pt), block 320.
// variant0 (pt=w*128+h): q->qdH[W][H][32], k->pkc[0][w][h][32], v->pvc[0][w][h][256]
// variant1 (pt=h*128+w): q->qdW[H][W][32], k->kdW[H][W][32],   v->vdW[H][W][256]
// ---------------------------------------------------------------------------
__global__ __launch_bounds__(320) void k_sample(
    const u16* __restrict__ pqk, const u16* __restrict__ pvx,
    const float* __restrict__ dX, const float* __restrict__ dY,
    u16* __restrict__ qdH, u16* __restrict__ pkc, u16* __restrict__ pvc,
    u16* __restrict__ qdW, u16* __restrict__ kdW, u16* __restrict__ vdW)
{
    int bid = blockIdx.x;
    int variant = bid >> 14;
    int pt = bid & 16383;
    int t = threadIdx.x;
    int w, h;
    float xn, yn;
    if (variant == 0) {
        w = pt >> 7; h = pt & 127;
        xn = (-1.0f + (float)w     * (2.0f/128.0f)) + dX[(h+1)*2 + 0];
        yn = (-1.0f + (float)(h+1) * (2.0f/128.0f)) + dX[(h+1)*2 + 1];
    } else {
        h = pt >> 7; w = pt & 127;
        xn = (-1.0f + (float)(w+1) * (2.0f/128.0f)) + dY[(w+1)*2 + 0];
        yn = (-1.0f + (float)h     * (2.0f/128.0f)) + dY[(w+1)*2 + 1];
    }
    float fx = (xn + 1.0f) * 0.5f * 127.0f;
    float fy = (yn + 1.0f) * 0.5f * 127.0f;
    float x0f = floorf(fx), y0f = floorf(fy);
    float wx = fx - x0f, wy = fy - y0f;

    float wt[4]; int xi[4], yi[4]; bool vd[4];
    {
        float xs[2]  = { x0f, x0f + 1.0f };
        float ys[2]  = { y0f, y0f + 1.0f };
        float wxs[2] = { 1.0f - wx, wx };
        float wys[2] = { 1.0f - wy, wy };
        #pragma unroll
        for (int jy = 0; jy < 2; ++jy)
            #pragma unroll
            for (int jx = 0; jx < 2; ++jx) {
                int k = jy*2 + jx;
                vd[k] = (xs[jx] >= 0.f) && (xs[jx] < 128.f) && (ys[jy] >= 0.f) && (ys[jy] < 128.f);
                wt[k] = wxs[jx] * wys[jy];
                xi[k] = (int)fminf(fmaxf(xs[jx], 0.f), 127.f);
                yi[k] = (int)fminf(fmaxf(ys[jy], 0.f), 127.f);
            }
    }
    float val = 0.f;
    if (t < 64) {
        #pragma unroll
        for (int k = 0; k < 4; ++k)
            if (vd[k]) val += wt[k] * b2f(pqk[(size_t)(yi[k]*128 + xi[k])*64 + t]);
        if (t < 32) {
            if (variant == 0) qdH[(size_t)pt*32 + t] = f2b(val);
            else              qdW[(size_t)pt*32 + t] = f2b(val);
        } else {
            int c = t - 32;
            if (variant == 0) pkc[(size_t)pt*32 + c] = f2b(val);
            else              kdW[(size_t)pt*32 + c] = f2b(val);
        }
    } else {
        int c = t - 64;
        #pragma unroll
        for (int k = 0; k < 4; ++k)
            if (vd[k]) val += wt[k] * b2f(pvx[(size_t)(yi[k]*128 + xi[k])*256 + c]);
        if (variant == 0) pvc[(size_t)pt*256 + c] = f2b(val);
        else              vdW[(size_t)pt*256 + c] = f2b(val);
    }
}

// ---------------------------------------------------------------------------
// K3: fused scores + joint softmax.  block per (b,h), 256 threads.
// ---------------------------------------------------------------------------
__global__ __launch_bounds__(256) void k_fused(
    const u16* __restrict__ pqk, const u16* __restrict__ pkc,
    const u16* __restrict__ qdH, const u16* __restrict__ qdW, const u16* __restrict__ kdW,
    u16* __restrict__ attbH, u16* __restrict__ attbW)
{
    int b = blockIdx.x >> 7, h = blockIdx.x & 127;
    int t = threadIdx.x;
    __shared__ float qr[128*33];   // row-line q  [w][c]
    __shared__ float kr[128*33];   // row-line k  [j][c]
    __shared__ float qc[128*33];   // col-line q  [w][c]   (b==0 only; b!=0 -> qr)
    __shared__ float mh[256], zh[256];
    __shared__ float Mw[128], Iw[128];

    if (b == 0) {
        for (int i = t; i < 4096; i += 256) {
            int w = i >> 5, c = i & 31;
            qr[w*33 + c] = b2f(qdW[(size_t)h*4096 + i]);
            kr[w*33 + c] = b2f(kdW[(size_t)h*4096 + i]);
            qc[w*33 + c] = b2f(qdH[((size_t)w*128 + h)*32 + c]);
        }
    } else {
        size_t base = ((size_t)b*16384 + h*128)*64;
        for (int i = t; i < 4096; i += 256) {
            int w = i >> 5, c = i & 31;
            qr[w*33 + c] = b2f(pqk[base + w*64 + c]);
            kr[w*33 + c] = b2f(pqk[base + w*64 + 32 + c]);
        }
    }
    __syncthreads();
    const float* qcp = (b == 0) ? qc : qr;

    // ---- pass A: online max/sum.  lane = w; kind0 = col scores, kind1 = row.
    int w = t & 127, kind = t >> 7;
    float qreg[32];
    {
        const float* qsrc = kind ? (qr + w*33) : (qcp + w*33);
        #pragma unroll
        for (int c = 0; c < 32; ++c) qreg[c] = qsrc[c];
    }
    float m = -INFINITY, Z = 0.f;
    if (kind == 0) {
        const u16* ksrc = pkc + ((size_t)(b*128 + w))*4096;
        for (int j = 0; j < 128; ++j) {
            if (j == h) continue;
            float s = dot32g(qreg, ksrc + j*32);
            float mn = fmaxf(m, s);
            Z = Z * __expf(m - mn) + __expf(s - mn);
            m = mn;
        }
    } else {
        for (int j = 0; j < 128; ++j) {
            float s = dot32f(qreg, kr + j*33);
            float mn = fmaxf(m, s);
            Z = Z * __expf(m - mn) + __expf(s - mn);
            m = mn;
        }
    }
    mh[t] = m; zh[t] = Z;
    __syncthreads();
    if (t < 128) {
        float m0 = mh[t], m1 = mh[128 + t];
        float M = fmaxf(m0, m1);
        float Zt = zh[t] * __expf(m0 - M) + zh[128 + t] * __expf(m1 - M);
        Mw[t] = M; Iw[t] = 1.0f / Zt;
    }
    __syncthreads();

    // ---- pass B: recompute scores, write normalized bf16 probs. lane = j.
    int j = t & 127;
    if (kind == 0) {
        const u16* ksrc; size_t wstride;
        if (b == 0) { ksrc = pkc + (size_t)j*32;                              wstride = 4096; }
        else        { ksrc = pqk + ((size_t)(b*16384 + j*128))*64 + 32;       wstride = 64;   }
        u16* dst = attbH + ((size_t)(b*128 + h)*128)*128 + j;
        if (j == h) {
            for (int w2 = 0; w2 < 128; ++w2) dst[(size_t)w2*128] = 0;
        } else {
            for (int w2 = 0; w2 < 128; ++w2) {
                float s = dot32g(qcp + w2*33, ksrc + (size_t)w2 * wstride);
                float p = __expf(s - Mw[w2]) * Iw[w2];
                dst[(size_t)w2*128] = f2b(p);
            }
        }
    } else {
        u16* dst = attbW + ((size_t)(b*128 + h)*128)*128 + j;
        for (int w2 = 0; w2 < 128; ++w2) {
            float s = dot32f(qr + w2*33, kr + j*33);
            float p = __expf(s - Mw[w2]) * Iw[w2];
            dst[(size_t)w2*128] = f2b(p);
        }
    }
}

// ---------------------------------------------------------------------------
// K4: column aggregation -> outH into d_out.
// out[b][c][k][w] = sum_h pvc[b][w][h][c] * attbH[b,k,w,h].  block (b,w), thread=c.
// ---------------------------------------------------------------------------
__global__ __launch_bounds__(256) void k_outcol(const u16* __restrict__ pvc,
    const u16* __restrict__ attbH, void* __restrict__ out, const int* __restrict__ flag)
{
    bool f32 = flag[0] != 0;
    int b = blockIdx.x >> 7, w = blockIdx.x & 127;
    int t = threadIdx.x;
    __shared__ float al[128*128];   // [h_key][k_query]
    {
        int k = t & 127;
        int hbase = (t >> 7) * 64;
        for (int i = 0; i < 8; ++i) {
            int hh = hbase + i*8;
            size_t g = ((size_t)(b*128 + k)*128 + w)*128 + hh;
            uint4 u = *reinterpret_cast<const uint4*>(attbH + g);
            u32 uu[4] = { u.x, u.y, u.z, u.w };
            #pragma unroll
            for (int q = 0; q < 4; ++q) {
                al[(hh + 2*q    )*128 + k] = __uint_as_float(uu[q] << 16);
                al[(hh + 2*q + 1)*128 + k] = __uint_as_float(uu[q] & 0xffff0000u);
            }
        }
    }
    int c = t;
    const u16* vsrc = pvc + (((size_t)(b*128 + w))*128)*256 + c;
    u32 vp[64];
    for (int i = 0; i < 64; ++i) {
        u32 lo = vsrc[(size_t)(2*i)   * 256];
        u32 hi = vsrc[(size_t)(2*i+1) * 256];
        vp[i] = lo | (hi << 16);
    }
    __syncthreads();
    for (int kc = 0; kc < 8; ++kc) {
        int k0 = kc * 16;
        float acc[16];
        #pragma unroll
        for (int kk = 0; kk < 16; ++kk) acc[kk] = 0.f;
        for (int hp = 0; hp < 64; ++hp) {
            u32 p = vp[hp];
            float v0 = __uint_as_float(p << 16);
            float v1 = __uint_as_float(p & 0xffff0000u);
            const float4* a0 = reinterpret_cast<const float4*>(&al[(2*hp)*128 + k0]);
            const float4* a1 = reinterpret_cast<const float4*>(&al[(2*hp+1)*128 + k0]);
            #pragma unroll
            for (int q = 0; q < 4; ++q) {
                float4 x0 = a0[q], x1 = a1[q];
                acc[q*4+0] += v0*x0.x; acc[q*4+1] += v0*x0.y; acc[q*4+2] += v0*x0.z; acc[q*4+3] += v0*x0.w;
                acc[q*4+0] += v1*x1.x; acc[q*4+1] += v1*x1.y; acc[q*4+2] += v1*x1.z; acc[q*4+3] += v1*x1.w;
            }
        }
        #pragma unroll
        for (int kk = 0; kk < 16; ++kk)
            stout(out, ((size_t)(b*256 + c)*128 + (k0 + kk))*128 + w, acc[kk], f32);
    }
}

// ---------------------------------------------------------------------------
// K5: row aggregation + epilogue.
// out[b][c][h][k] = gamma*(outH + sum_j v[c,h,j]*attbW[b,h,k,j]) + x
// ---------------------------------------------------------------------------
__global__ __launch_bounds__(256) void k_outrow(const u16* __restrict__ pvx, const u16* __restrict__ vdW,
    const u16* __restrict__ attbW, const void* __restrict__ xraw,
    const void* __restrict__ gamma, void* __restrict__ out, const int* __restrict__ flag)
{
    bool f32 = flag[0] != 0;
    int b = blockIdx.x >> 7, h = blockIdx.x & 127;
    int t = threadIdx.x;
    __shared__ float al[128*128];   // [j_key][k_query]
    {
        int k = t & 127;
        int jbase = (t >> 7) * 64;
        for (int i = 0; i < 8; ++i) {
            int jj = jbase + i*8;
            size_t g = ((size_t)(b*128 + h)*128 + k)*128 + jj;
            uint4 u = *reinterpret_cast<const uint4*>(attbW + g);
            u32 uu[4] = { u.x, u.y, u.z, u.w };
            #pragma unroll
            for (int q = 0; q < 4; ++q) {
                al[(jj + 2*q    )*128 + k] = __uint_as_float(uu[q] << 16);
                al[(jj + 2*q + 1)*128 + k] = __uint_as_float(uu[q] & 0xffff0000u);
            }
        }
    }
    int c = t;
    const u16* vsrc = (b == 0) ? (vdW + (size_t)h*128*256 + c)
                               : (pvx + ((size_t)b*16384 + h*128)*256 + c);
    u32 vp[64];
    for (int i = 0; i < 64; ++i) {
        u32 lo = vsrc[(size_t)(2*i)   * 256];
        u32 hi = vsrc[(size_t)(2*i+1) * 256];
        vp[i] = lo | (hi << 16);
    }
    float gm = ldin(gamma, 0, f32);
    __syncthreads();
    for (int kc = 0; kc < 8; ++kc) {
        int k0 = kc * 16;
        float acc[16];
        #pragma unroll
        for (int kk = 0; kk < 16; ++kk) acc[kk] = 0.f;
        for (int jp = 0; jp < 64; ++jp) {
            u32 p = vp[jp];
            float v0 = __uint_as_float(p << 16);
            float v1 = __uint_as_float(p & 0xffff0000u);
            const float4* a0 = reinterpret_cast<const float4*>(&al[(2*jp)*128 + k0]);
            const float4* a1 = reinterpret_cast<const float4*>(&al[(2*jp+1)*128 + k0]);
            #pragma unroll
            for (int q = 0; q < 4; ++q) {
                float4 x0 = a0[q], x1 = a1[q];
                acc[q*4+0] += v0*x0.x; acc[q*4+1] += v0*x0.y; acc[q*4+2] += v0*x0.z; acc[q*4+3] += v0*x0.w;
                acc[q*4+0] += v1*x1.x; acc[q*4+1] += v1*x1.y; acc[q*4+2] += v1*x1.z; acc[q*4+3] += v1*x1.w;
            }
        }
        size_t base = ((size_t)(b*256 + c)*128 + h)*128 + k0;
        #pragma unroll
        for (int kk = 0; kk < 16; ++kk) {
            size_t idx = base + kk;
            float hst = ldout(out, idx, f32);
            float xv  = ldin(xraw, idx, f32);
            float v = gm * (hst + acc[kk]) + xv;
            if (!(v == v)) v = -299.f;
            stout(out, idx, v, f32);
        }
    }
}

// ---------------------------------------------------------------------------
extern "C" void kernel_launch(void* const* d_in, const int* in_sizes, int n_in,
                              void* d_out, int out_size, void* d_ws, size_t ws_size,
                              hipStream_t stream)
{
    const void* x     = d_in[0];
    const void* Wq    = d_in[1];
    const void* bq    = d_in[2];
    const void* Wk    = d_in[3];
    const void* bk    = d_in[4];
    const void* Wv    = d_in[5];
    const void* bv    = d_in[6];
    const void* gamma = d_in[7];
    const void* off   = d_in[8];

    char* ws = (char*)d_ws;
    size_t o = 0;
    auto alloc = [&](size_t bytes) { size_t r = o; o += (bytes + 255) & ~(size_t)255; return r; };
    int*   flag = (int*)(ws + alloc(256));
    float* dX   = (float*)(ws + alloc(129*2*4));
    float* dY   = (float*)(ws + alloc(129*2*4));
    u16*   pqk  = (u16*)(ws + alloc((size_t)4*16384*64*2));     // [B][HW][64]
    u16*   pvx  = (u16*)(ws + alloc((size_t)4*16384*256*2));    // [B][HW][256]
    u16*   pkc  = (u16*)(ws + alloc((size_t)4*128*128*32*2));   // [B][W][H][32]  (b0 = sampled)
    u16*   pvc  = (u16*)(ws + alloc((size_t)4*128*128*256*2));  // [B][W][H][256] (b0 = sampled)
    u16*   qdH  = (u16*)(ws + alloc((size_t)16384*32*2));       // [W][H][32]
    u16*   qdW  = (u16*)(ws + alloc((size_t)16384*32*2));       // [H][W][32]
    u16*   kdW  = (u16*)(ws + alloc((size_t)16384*32*2));
    u16*   vdW  = (u16*)(ws + alloc((size_t)16384*256*2));      // [H][W][256]
    u16*   attbH= (u16*)(ws + alloc((size_t)4*128*128*128*2));  // [B][H][W][128]
    u16*   attbW= (u16*)(ws + alloc((size_t)4*128*128*128*2));

    k_detect   <<<1, 256, 0, stream>>>(x, flag);
    k_setup    <<<1, 256, 0, stream>>>(off, dX, dY, d_out, flag);
    k_proj_mfma<<<dim3(5, 512), 256, 0, stream>>>(x, Wq, bq, Wk, bk, Wv, bv, pqk, pvx, flag);
    k_transqk  <<<192, 256, 0, stream>>>(pqk, pkc);
    k_transv   <<<6144, 256, 0, stream>>>(pvx, pvc);
    k_sample   <<<32768, 320, 0, stream>>>(pqk, pvx, dX, dY, qdH, pkc, pvc, qdW, kdW, vdW);
    k_fused    <<<512, 256, 0, stream>>>(pqk, pkc, qdH, qdW, kdW, attbH, attbW);
    k_outcol   <<<512, 256, 0, stream>>>(pvc, attbH, d_out, flag);
    k_outrow   <<<512, 256, 0, stream>>>(pvx, vdW, attbW, x, gamma, d_out, flag);
    (void)in_sizes; (void)n_in; (void)out_size; (void)ws_size;
}

// Round 5
// 854.713 us; speedup vs baseline: 2.9498x; 1.5238x over previous
//
#include <hip/hip_runtime.h>
#include <hip/hip_bf16.h>

typedef unsigned short u16;
typedef unsigned int   u32;
typedef short bf16x8 __attribute__((ext_vector_type(8)));
typedef float f32x4  __attribute__((ext_vector_type(4)));

__device__ __forceinline__ float b2f(u16 u) {
    return __uint_as_float(((u32)u) << 16);
}
__device__ __forceinline__ u16 f2b(float f) {
    __hip_bfloat16 h = __float2bfloat16(f);
    u16 r; __builtin_memcpy(&r, &h, 2); return r;
}
// dtype-adaptive input load / output store (flag: 1 = fp32, 0 = bf16)
__device__ __forceinline__ float ldin(const void* p, size_t i, bool f32) {
    return f32 ? ((const float*)p)[i] : b2f(((const u16*)p)[i]);
}
__device__ __forceinline__ void stout(void* p, size_t i, float v, bool f32) {
    if (f32) ((float*)p)[i] = v; else ((u16*)p)[i] = f2b(v);
}

// dot of 32 fp32 (q) with 32 bf16 (global, 64B-aligned)
__device__ __forceinline__ float dot32g(const float* q, const u16* kp) {
    const uint4* k4 = reinterpret_cast<const uint4*>(kp);
    float s = 0.f;
    #pragma unroll
    for (int i = 0; i < 4; ++i) {
        uint4 u = k4[i];
        u32 uu[4] = {u.x, u.y, u.z, u.w};
        #pragma unroll
        for (int q2 = 0; q2 < 4; ++q2) {
            s += q[i*8 + q2*2]     * __uint_as_float(uu[q2] << 16);
            s += q[i*8 + q2*2 + 1] * __uint_as_float(uu[q2] & 0xffff0000u);
        }
    }
    return s;
}
__device__ __forceinline__ float dot32f(const float* q, const float* k) {
    float s = 0.f;
    #pragma unroll
    for (int c = 0; c < 32; ++c) s += q[c] * k[c];
    return s;
}

// ---------------------------------------------------------------------------
// K-1: dtype detector (fp32 low halves ~ uniform bits -> bf16-NaN patterns).
// ---------------------------------------------------------------------------
__global__ __launch_bounds__(256) void k_detect(const void* __restrict__ xraw, int* __restrict__ flag)
{
    const uint4* xv = (const uint4*)xraw;
    int t = threadIdx.x;
    int cnt = 0;
    for (int i = t; i < 8192; i += 256) {
        uint4 u = xv[i];
        u32 uu[4] = {u.x, u.y, u.z, u.w};
        #pragma unroll
        for (int q = 0; q < 4; ++q) {
            u16 a = (u16)(uu[q] & 0xffff), b = (u16)(uu[q] >> 16);
            if ((a & 0x7F80u) == 0x7F80u && (a & 0x007Fu) != 0) cnt++;
            if ((b & 0x7F80u) == 0x7F80u && (b & 0x007Fu) != 0) cnt++;
        }
    }
    __shared__ int red[256];
    red[t] = cnt; __syncthreads();
    for (int st = 128; st > 0; st >>= 1) {
        if (t < st) red[t] += red[t + st];
        __syncthreads();
    }
    if (t == 0) flag[0] = (red[0] > 16) ? 1 : 0;
}

// ---------------------------------------------------------------------------
// K0: pooled offset lines (dX, dY) + regloss.  offsets [2][131][131]
// ---------------------------------------------------------------------------
__global__ __launch_bounds__(256) void k_setup(const void* __restrict__ off,
                                               float* __restrict__ dX, float* __restrict__ dY,
                                               void* __restrict__ out, const int* __restrict__ flag) {
    bool f32 = flag[0] != 0;
    int t = threadIdx.x;
    if (t < 129) {
        for (int ch = 0; ch < 2; ++ch) {
            float s1 = 0.f, s2 = 0.f;
            for (int i = 0; i < 3; ++i)
                for (int j = 0; j < 3; ++j) {
                    s1 += ldin(off, ch*17161 + (t+i)*131 + (64+j), f32);
                    s2 += ldin(off, ch*17161 + (64+i)*131 + (t+j), f32);
                }
            dX[t*2 + ch] = s1 * (1.0f/9.0f);
            dY[t*2 + ch] = s2 * (1.0f/9.0f);
        }
    }
    float s = 0.f;
    for (int idx = t; idx < 17161; idx += 256) {
        float d = ldin(off, idx, f32) - ldin(off, 17161 + idx, f32);
        s += d * d * (1.0f/17161.0f);
    }
    for (int idx = t; idx < 34060; idx += 256) {
        int ch = idx / 17030;
        int rem = idx - ch*17030;
        int r = rem / 131, c = rem - r*131;
        float a = ldin(off, ch*17161 + r*131 + c, f32);
        float b = ldin(off, ch*17161 + (r+1)*131 + c, f32);
        float d = a - b;
        s += d * d * (1.0f/34060.0f);
    }
    __shared__ float red[256];
    red[t] = s; __syncthreads();
    for (int st = 128; st > 0; st >>= 1) {
        if (t < st) red[t] += red[t + st];
        __syncthreads();
    }
    if (t == 0) {
        float v = red[0];
        if (!(v == v)) v = -299.f;
        stout(out, (size_t)16777216, v, f32);
    }
}

// ---------------------------------------------------------------------------
// K1: MFMA projections.  GEMM W[320,256] x X[256, B*HW].
// W split into bf16 hi+lo (keeps ~fp32 weight precision, 2 chained MFMAs).
// Outputs: pqk bf16 [B][HW][64] (q=0..31,k=32..63); pvx bf16 [B][HW][256].
// ---------------------------------------------------------------------------
__global__ __launch_bounds__(256) void k_proj_mfma(
    const void* __restrict__ xraw,
    const void* Wq, const void* bq, const void* Wk, const void* bk,
    const void* Wv, const void* bv,
    u16* __restrict__ pqk, u16* __restrict__ pvx, const int* __restrict__ flag)
{
    bool f32 = flag[0] != 0;
    int t = threadIdx.x;
    int ot = blockIdx.x;                 // 0..4
    int gp = blockIdx.y * 128;
    int b  = gp >> 14;
    int p0 = gp & 16383;
    int o_base = ot * 64;

    __shared__ __align__(16) u16 WH [64*32];
    __shared__ __align__(16) u16 WLo[64*32];
    __shared__ __align__(16) u16 XL [128*32];

    f32x4 acc[4][2];
    #pragma unroll
    for (int i = 0; i < 4; ++i)
        #pragma unroll
        for (int j = 0; j < 2; ++j) acc[i][j] = (f32x4){0.f, 0.f, 0.f, 0.f};

    int wid = t >> 6, lane = t & 63;
    int quad = lane >> 4, n = lane & 15;

    for (int kc = 0; kc < 8; ++kc) {
        int c0 = kc * 32;
        #pragma unroll
        for (int i = 0; i < 8; ++i) {
            int idx = i*256 + t;
            int o = idx >> 5, k = idx & 31;
            int og = o_base + o;
            const void* wsrc; int row;
            if (og < 32)      { wsrc = Wq; row = og; }
            else if (og < 64) { wsrc = Wk; row = og - 32; }
            else              { wsrc = Wv; row = og - 64; }
            float wv = ldin(wsrc, (size_t)row*256 + c0 + k, f32);
            u16 hi = f2b(wv);
            WH [o*32 + k] = hi;
            WLo[o*32 + k] = f2b(wv - b2f(hi));
        }
        #pragma unroll
        for (int i = 0; i < 8; ++i) {
            int idx = i*256 + t;
            int cp = idx >> 7;
            int px = idx & 127;
            size_t base = ((size_t)(b*256 + c0 + 2*cp))*16384 + p0 + px;
            u16 lo16, hi16;
            if (f32) {
                const float* xf = (const float*)xraw;
                lo16 = f2b(xf[base]); hi16 = f2b(xf[base + 16384]);
            } else {
                const u16* xu = (const u16*)xraw;
                lo16 = xu[base]; hi16 = xu[base + 16384];
            }
            *reinterpret_cast<u32*>(&XL[px*32 + 2*cp]) = (u32)lo16 | ((u32)hi16 << 16);
        }
        __syncthreads();
        bf16x8 bf0 = *reinterpret_cast<const bf16x8*>(&XL[(wid*32 +      n)*32 + quad*8]);
        bf16x8 bf1 = *reinterpret_cast<const bf16x8*>(&XL[(wid*32 + 16 + n)*32 + quad*8]);
        #pragma unroll
        for (int ot2 = 0; ot2 < 4; ++ot2) {
            bf16x8 ah = *reinterpret_cast<const bf16x8*>(&WH [(ot2*16 + n)*32 + quad*8]);
            bf16x8 al = *reinterpret_cast<const bf16x8*>(&WLo[(ot2*16 + n)*32 + quad*8]);
            acc[ot2][0] = __builtin_amdgcn_mfma_f32_16x16x32_bf16(ah, bf0, acc[ot2][0], 0, 0, 0);
            acc[ot2][0] = __builtin_amdgcn_mfma_f32_16x16x32_bf16(al, bf0, acc[ot2][0], 0, 0, 0);
            acc[ot2][1] = __builtin_amdgcn_mfma_f32_16x16x32_bf16(ah, bf1, acc[ot2][1], 0, 0, 0);
            acc[ot2][1] = __builtin_amdgcn_mfma_f32_16x16x32_bf16(al, bf1, acc[ot2][1], 0, 0, 0);
        }
        __syncthreads();
    }
    #pragma unroll
    for (int ot2 = 0; ot2 < 4; ++ot2) {
        int o_l = ot2*16 + quad*4;
        int og  = o_base + o_l;
        const void* bsrc; int boff;
        if (og < 32)      { bsrc = bq; boff = og; }
        else if (og < 64) { bsrc = bk; boff = og - 32; }
        else              { bsrc = bv; boff = og - 64; }
        float b0 = ldin(bsrc, boff,   f32), b1 = ldin(bsrc, boff+1, f32);
        float b2 = ldin(bsrc, boff+2, f32), b3 = ldin(bsrc, boff+3, f32);
        #pragma unroll
        for (int pt = 0; pt < 2; ++pt) {
            f32x4 a = acc[ot2][pt];
            int px = p0 + wid*32 + pt*16 + n;
            u32 w0 = (u32)f2b(a[0] + b0) | ((u32)f2b(a[1] + b1) << 16);
            u32 w1 = (u32)f2b(a[2] + b2) | ((u32)f2b(a[3] + b3) << 16);
            u16* dst;
            if (ot == 0) dst = pqk + ((size_t)(b*16384 + px))*64  + o_l;
            else         dst = pvx + ((size_t)(b*16384 + px))*256 + (o_base - 64 + o_l);
            *reinterpret_cast<uint2*>(dst) = make_uint2(w0, w1);
        }
    }
}

// ---------------------------------------------------------------------------
// K1b: transpose k-half of pqk into col-major pkc[B][W][H][32]  (b>=1 only).
// ---------------------------------------------------------------------------
__global__ __launch_bounds__(256) void k_transqk(const u16* __restrict__ pqk, u16* __restrict__ pkc)
{
    int pg = 16384 + blockIdx.x*256 + threadIdx.x;
    int b = pg >> 14, hw = pg & 16383, h = hw >> 7, w = hw & 127;
    const uint4* src = reinterpret_cast<const uint4*>(pqk + (size_t)pg*64 + 32);
    uint4* dst = reinterpret_cast<uint4*>(pkc + (((size_t)(b*128 + w))*128 + h)*32);
    #pragma unroll
    for (int i = 0; i < 4; ++i) dst[i] = src[i];
}

// ---------------------------------------------------------------------------
// K1c: transpose pvx into col-major pvc[B][W][H][256]  (b>=1 only).
// ---------------------------------------------------------------------------
__global__ __launch_bounds__(256) void k_transv(const u16* __restrict__ pvx, u16* __restrict__ pvc)
{
    int t = threadIdx.x;
    int p = 16384 + blockIdx.x*8 + (t >> 5);
    int c = (t & 31)*8;
    int b = p >> 14, hw = p & 16383, h = hw >> 7, w = hw & 127;
    *reinterpret_cast<uint4*>(pvc + (((size_t)(b*128 + w))*128 + h)*256 + c) =
        *reinterpret_cast<const uint4*>(pvx + (size_t)p*256 + c);
}

// ---------------------------------------------------------------------------
// K2: deformed bilinear sampling for batch 0.
// ---------------------------------------------------------------------------
__global__ __launch_bounds__(320) void k_sample(
    const u16* __restrict__ pqk, const u16* __restrict__ pvx,
    const float* __restrict__ dX, const float* __restrict__ dY,
    u16* __restrict__ qdH, u16* __restrict__ pkc, u16* __restrict__ pvc,
    u16* __restrict__ qdW, u16* __restrict__ kdW, u16* __restrict__ vdW)
{
    int bid = blockIdx.x;
    int variant = bid >> 14;
    int pt = bid & 16383;
    int t = threadIdx.x;
    int w, h;
    float xn, yn;
    if (variant == 0) {
        w = pt >> 7; h = pt & 127;
        xn = (-1.0f + (float)w     * (2.0f/128.0f)) + dX[(h+1)*2 + 0];
        yn = (-1.0f + (float)(h+1) * (2.0f/128.0f)) + dX[(h+1)*2 + 1];
    } else {
        h = pt >> 7; w = pt & 127;
        xn = (-1.0f + (float)(w+1) * (2.0f/128.0f)) + dY[(w+1)*2 + 0];
        yn = (-1.0f + (float)h     * (2.0f/128.0f)) + dY[(w+1)*2 + 1];
    }
    float fx = (xn + 1.0f) * 0.5f * 127.0f;
    float fy = (yn + 1.0f) * 0.5f * 127.0f;
    float x0f = floorf(fx), y0f = floorf(fy);
    float wx = fx - x0f, wy = fy - y0f;

    float wt[4]; int xi[4], yi[4]; bool vd[4];
    {
        float xs[2]  = { x0f, x0f + 1.0f };
        float ys[2]  = { y0f, y0f + 1.0f };
        float wxs[2] = { 1.0f - wx, wx };
        float wys[2] = { 1.0f - wy, wy };
        #pragma unroll
        for (int jy = 0; jy < 2; ++jy)
            #pragma unroll
            for (int jx = 0; jx < 2; ++jx) {
                int k = jy*2 + jx;
                vd[k] = (xs[jx] >= 0.f) && (xs[jx] < 128.f) && (ys[jy] >= 0.f) && (ys[jy] < 128.f);
                wt[k] = wxs[jx] * wys[jy];
                xi[k] = (int)fminf(fmaxf(xs[jx], 0.f), 127.f);
                yi[k] = (int)fminf(fmaxf(ys[jy], 0.f), 127.f);
            }
    }
    float val = 0.f;
    if (t < 64) {
        #pragma unroll
        for (int k = 0; k < 4; ++k)
            if (vd[k]) val += wt[k] * b2f(pqk[(size_t)(yi[k]*128 + xi[k])*64 + t]);
        if (t < 32) {
            if (variant == 0) qdH[(size_t)pt*32 + t] = f2b(val);
            else              qdW[(size_t)pt*32 + t] = f2b(val);
        } else {
            int c = t - 32;
            if (variant == 0) pkc[(size_t)pt*32 + c] = f2b(val);
            else              kdW[(size_t)pt*32 + c] = f2b(val);
        }
    } else {
        int c = t - 64;
        #pragma unroll
        for (int k = 0; k < 4; ++k)
            if (vd[k]) val += wt[k] * b2f(pvx[(size_t)(yi[k]*128 + xi[k])*256 + c]);
        if (variant == 0) pvc[(size_t)pt*256 + c] = f2b(val);
        else              vdW[(size_t)pt*256 + c] = f2b(val);
    }
}

// ---------------------------------------------------------------------------
// K3: fused scores + joint softmax.  block per (b,h), 256 threads.
// ---------------------------------------------------------------------------
__global__ __launch_bounds__(256) void k_fused(
    const u16* __restrict__ pqk, const u16* __restrict__ pkc,
    const u16* __restrict__ qdH, const u16* __restrict__ qdW, const u16* __restrict__ kdW,
    u16* __restrict__ attbH, u16* __restrict__ attbW)
{
    int b = blockIdx.x >> 7, h = blockIdx.x & 127;
    int t = threadIdx.x;
    __shared__ float qr[128*33];
    __shared__ float kr[128*33];
    __shared__ float qc[128*33];
    __shared__ float mh[256], zh[256];
    __shared__ float Mw[128], Iw[128];

    if (b == 0) {
        for (int i = t; i < 4096; i += 256) {
            int w = i >> 5, c = i & 31;
            qr[w*33 + c] = b2f(qdW[(size_t)h*4096 + i]);
            kr[w*33 + c] = b2f(kdW[(size_t)h*4096 + i]);
            qc[w*33 + c] = b2f(qdH[((size_t)w*128 + h)*32 + c]);
        }
    } else {
        size_t base = ((size_t)b*16384 + h*128)*64;
        for (int i = t; i < 4096; i += 256) {
            int w = i >> 5, c = i & 31;
            qr[w*33 + c] = b2f(pqk[base + w*64 + c]);
            kr[w*33 + c] = b2f(pqk[base + w*64 + 32 + c]);
        }
    }
    __syncthreads();
    const float* qcp = (b == 0) ? qc : qr;

    int w = t & 127, kind = t >> 7;
    float qreg[32];
    {
        const float* qsrc = kind ? (qr + w*33) : (qcp + w*33);
        #pragma unroll
        for (int c = 0; c < 32; ++c) qreg[c] = qsrc[c];
    }
    float m = -INFINITY, Z = 0.f;
    if (kind == 0) {
        const u16* ksrc = pkc + ((size_t)(b*128 + w))*4096;
        for (int j = 0; j < 128; ++j) {
            if (j == h) continue;
            float s = dot32g(qreg, ksrc + j*32);
            float mn = fmaxf(m, s);
            Z = Z * __expf(m - mn) + __expf(s - mn);
            m = mn;
        }
    } else {
        for (int j = 0; j < 128; ++j) {
            float s = dot32f(qreg, kr + j*33);
            float mn = fmaxf(m, s);
            Z = Z * __expf(m - mn) + __expf(s - mn);
            m = mn;
        }
    }
    mh[t] = m; zh[t] = Z;
    __syncthreads();
    if (t < 128) {
        float m0 = mh[t], m1 = mh[128 + t];
        float M = fmaxf(m0, m1);
        float Zt = zh[t] * __expf(m0 - M) + zh[128 + t] * __expf(m1 - M);
        Mw[t] = M; Iw[t] = 1.0f / Zt;
    }
    __syncthreads();

    int j = t & 127;
    if (kind == 0) {
        const u16* ksrc; size_t wstride;
        if (b == 0) { ksrc = pkc + (size_t)j*32;                              wstride = 4096; }
        else        { ksrc = pqk + ((size_t)(b*16384 + j*128))*64 + 32;       wstride = 64;   }
        u16* dst = attbH + ((size_t)(b*128 + h)*128)*128 + j;
        if (j == h) {
            for (int w2 = 0; w2 < 128; ++w2) dst[(size_t)w2*128] = 0;
        } else {
            for (int w2 = 0; w2 < 128; ++w2) {
                float s = dot32g(qcp + w2*33, ksrc + (size_t)w2 * wstride);
                float p = __expf(s - Mw[w2]) * Iw[w2];
                dst[(size_t)w2*128] = f2b(p);
            }
        }
    } else {
        u16* dst = attbW + ((size_t)(b*128 + h)*128)*128 + j;
        for (int w2 = 0; w2 < 128; ++w2) {
            float s = dot32f(qr + w2*33, kr + j*33);
            float p = __expf(s - Mw[w2]) * Iw[w2];
            dst[(size_t)w2*128] = f2b(p);
        }
    }
}

// ---------------------------------------------------------------------------
// K4: column aggregation -> T[b][w][h_out][c] bf16 (coalesced c-fast stores).
// T[b][w][k][c] = sum_h pvc[b][w][h][c] * attbH[b,k,w,h].  block (b,w), thread=c.
// ---------------------------------------------------------------------------
__global__ __launch_bounds__(256) void k_outcol(const u16* __restrict__ pvc,
    const u16* __restrict__ attbH, u16* __restrict__ T)
{
    int b = blockIdx.x >> 7, w = blockIdx.x & 127;
    int t = threadIdx.x;
    __shared__ float al[128*128];   // [h_key][k_query]
    {
        int k = t & 127;
        int hbase = (t >> 7) * 64;
        for (int i = 0; i < 8; ++i) {
            int hh = hbase + i*8;
            size_t g = ((size_t)(b*128 + k)*128 + w)*128 + hh;
            uint4 u = *reinterpret_cast<const uint4*>(attbH + g);
            u32 uu[4] = { u.x, u.y, u.z, u.w };
            #pragma unroll
            for (int q = 0; q < 4; ++q) {
                al[(hh + 2*q    )*128 + k] = __uint_as_float(uu[q] << 16);
                al[(hh + 2*q + 1)*128 + k] = __uint_as_float(uu[q] & 0xffff0000u);
            }
        }
    }
    int c = t;
    const u16* vsrc = pvc + (((size_t)(b*128 + w))*128)*256 + c;
    u32 vp[64];
    for (int i = 0; i < 64; ++i) {
        u32 lo = vsrc[(size_t)(2*i)   * 256];
        u32 hi = vsrc[(size_t)(2*i+1) * 256];
        vp[i] = lo | (hi << 16);
    }
    __syncthreads();
    u16* tdst = T + (((size_t)(b*128 + w))*128)*256 + c;
    for (int kc = 0; kc < 8; ++kc) {
        int k0 = kc * 16;
        float acc[16];
        #pragma unroll
        for (int kk = 0; kk < 16; ++kk) acc[kk] = 0.f;
        for (int hp = 0; hp < 64; ++hp) {
            u32 p = vp[hp];
            float v0 = __uint_as_float(p << 16);
            float v1 = __uint_as_float(p & 0xffff0000u);
            const float4* a0 = reinterpret_cast<const float4*>(&al[(2*hp)*128 + k0]);
            const float4* a1 = reinterpret_cast<const float4*>(&al[(2*hp+1)*128 + k0]);
            #pragma unroll
            for (int q = 0; q < 4; ++q) {
                float4 x0 = a0[q], x1 = a1[q];
                acc[q*4+0] += v0*x0.x; acc[q*4+1] += v0*x0.y; acc[q*4+2] += v0*x0.z; acc[q*4+3] += v0*x0.w;
                acc[q*4+0] += v1*x1.x; acc[q*4+1] += v1*x1.y; acc[q*4+2] += v1*x1.z; acc[q*4+3] += v1*x1.w;
            }
        }
        // coalesced: per kk, 256 lanes write 256 contiguous u16
        #pragma unroll
        for (int kk = 0; kk < 16; ++kk)
            tdst[(size_t)(k0 + kk) * 256] = f2b(acc[kk]);
    }
}

// ---------------------------------------------------------------------------
// K5: row aggregation + epilogue, vectorized.
// out[b][c][h][k] = gamma*(T[b][k][h][c] + sum_j v[c,h,j]*attbW[b,h,k,j]) + x
// block (b,h), thread = c.
// ---------------------------------------------------------------------------
__global__ __launch_bounds__(256) void k_outrow(const u16* __restrict__ pvx, const u16* __restrict__ vdW,
    const u16* __restrict__ attbW, const u16* __restrict__ T, const void* __restrict__ xraw,
    const void* __restrict__ gamma, void* __restrict__ out, const int* __restrict__ flag)
{
    bool f32 = flag[0] != 0;
    int b = blockIdx.x >> 7, h = blockIdx.x & 127;
    int t = threadIdx.x;
    __shared__ float al[128*128];   // [j_key][k_query]
    {
        int k = t & 127;
        int jbase = (t >> 7) * 64;
        for (int i = 0; i < 8; ++i) {
            int jj = jbase + i*8;
            size_t g = ((size_t)(b*128 + h)*128 + k)*128 + jj;
            uint4 u = *reinterpret_cast<const uint4*>(attbW + g);
            u32 uu[4] = { u.x, u.y, u.z, u.w };
            #pragma unroll
            for (int q = 0; q < 4; ++q) {
                al[(jj + 2*q    )*128 + k] = __uint_as_float(uu[q] << 16);
                al[(jj + 2*q + 1)*128 + k] = __uint_as_float(uu[q] & 0xffff0000u);
            }
        }
    }
    int c = t;
    const u16* vsrc = (b == 0) ? (vdW + (size_t)h*128*256 + c)
                               : (pvx + ((size_t)b*16384 + h*128)*256 + c);
    u32 vp[64];
    for (int i = 0; i < 64; ++i) {
        u32 lo = vsrc[(size_t)(2*i)   * 256];
        u32 hi = vsrc[(size_t)(2*i+1) * 256];
        vp[i] = lo | (hi << 16);
    }
    float gm = ldin(gamma, 0, f32);
    const u16* tsrc = T + ((size_t)(b*128))*128*256 + (size_t)h*256 + c;   // + k*32768
    __syncthreads();
    for (int kc = 0; kc < 8; ++kc) {
        int k0 = kc * 16;
        float acc[16];
        #pragma unroll
        for (int kk = 0; kk < 16; ++kk) acc[kk] = 0.f;
        for (int jp = 0; jp < 64; ++jp) {
            u32 p = vp[jp];
            float v0 = __uint_as_float(p << 16);
            float v1 = __uint_as_float(p & 0xffff0000u);
            const float4* a0 = reinterpret_cast<const float4*>(&al[(2*jp)*128 + k0]);
            const float4* a1 = reinterpret_cast<const float4*>(&al[(2*jp+1)*128 + k0]);
            #pragma unroll
            for (int q = 0; q < 4; ++q) {
                float4 x0 = a0[q], x1 = a1[q];
                acc[q*4+0] += v0*x0.x; acc[q*4+1] += v0*x0.y; acc[q*4+2] += v0*x0.z; acc[q*4+3] += v0*x0.w;
                acc[q*4+0] += v1*x1.x; acc[q*4+1] += v1*x1.y; acc[q*4+2] += v1*x1.z; acc[q*4+3] += v1*x1.w;
            }
        }
        // outH gather from T: per kk, lanes read 256 contiguous u16 (coalesced)
        float r[16];
        #pragma unroll
        for (int kk = 0; kk < 16; ++kk) {
            float hst = b2f(tsrc[(size_t)(k0 + kk) * 32768]);
            float v = gm * (hst + acc[kk]);
            r[kk] = v;
        }
        size_t base = ((size_t)(b*256 + c)*128 + h)*128 + k0;
        if (f32) {
            const float4* xv = reinterpret_cast<const float4*>((const float*)xraw + base);
            float4* ov = reinterpret_cast<float4*>((float*)out + base);
            #pragma unroll
            for (int q = 0; q < 4; ++q) {
                float4 xx = xv[q];
                float4 rr;
                rr.x = r[q*4+0] + xx.x; rr.y = r[q*4+1] + xx.y;
                rr.z = r[q*4+2] + xx.z; rr.w = r[q*4+3] + xx.w;
                if (!(rr.x == rr.x)) rr.x = -299.f;
                if (!(rr.y == rr.y)) rr.y = -299.f;
                if (!(rr.z == rr.z)) rr.z = -299.f;
                if (!(rr.w == rr.w)) rr.w = -299.f;
                ov[q] = rr;
            }
        } else {
            const uint4* xv = reinterpret_cast<const uint4*>((const u16*)xraw + base);
            uint4* ov = reinterpret_cast<uint4*>((u16*)out + base);
            #pragma unroll
            for (int q = 0; q < 2; ++q) {
                uint4 xx = xv[q];
                u32 xu[4] = { xx.x, xx.y, xx.z, xx.w };
                u32 ou[4];
                #pragma unroll
                for (int p2 = 0; p2 < 4; ++p2) {
                    int e = q*8 + p2*2;
                    float xlo = __uint_as_float(xu[p2] << 16);
                    float xhi = __uint_as_float(xu[p2] & 0xffff0000u);
                    float olo = r[e]   + xlo;
                    float ohi = r[e+1] + xhi;
                    if (!(olo == olo)) olo = -299.f;
                    if (!(ohi == ohi)) ohi = -299.f;
                    ou[p2] = (u32)f2b(olo) | ((u32)f2b(ohi) << 16);
                }
                ov[q] = make_uint4(ou[0], ou[1], ou[2], ou[3]);
            }
        }
    }
}

// ---------------------------------------------------------------------------
extern "C" void kernel_launch(void* const* d_in, const int* in_sizes, int n_in,
                              void* d_out, int out_size, void* d_ws, size_t ws_size,
                              hipStream_t stream)
{
    const void* x     = d_in[0];
    const void* Wq    = d_in[1];
    const void* bq    = d_in[2];
    const void* Wk    = d_in[3];
    const void* bk    = d_in[4];
    const void* Wv    = d_in[5];
    const void* bv    = d_in[6];
    const void* gamma = d_in[7];
    const void* off   = d_in[8];

    char* ws = (char*)d_ws;
    size_t o = 0;
    auto alloc = [&](size_t bytes) { size_t r = o; o += (bytes + 255) & ~(size_t)255; return r; };
    int*   flag = (int*)(ws + alloc(256));
    float* dX   = (float*)(ws + alloc(129*2*4));
    float* dY   = (float*)(ws + alloc(129*2*4));
    u16*   pqk  = (u16*)(ws + alloc((size_t)4*16384*64*2));     // [B][HW][64]
    u16*   pvx  = (u16*)(ws + alloc((size_t)4*16384*256*2));    // [B][HW][256]
    u16*   pkc  = (u16*)(ws + alloc((size_t)4*128*128*32*2));   // [B][W][H][32]
    u16*   pvc  = (u16*)(ws + alloc((size_t)4*128*128*256*2));  // [B][W][H][256]
    u16*   qdH  = (u16*)(ws + alloc((size_t)16384*32*2));
    u16*   qdW  = (u16*)(ws + alloc((size_t)16384*32*2));
    u16*   kdW  = (u16*)(ws + alloc((size_t)16384*32*2));
    u16*   vdW  = (u16*)(ws + alloc((size_t)16384*256*2));      // [H][W][256]
    u16*   attbH= (u16*)(ws + alloc((size_t)4*128*128*128*2));  // [B][H][W][128]
    u16*   attbW= (u16*)(ws + alloc((size_t)4*128*128*128*2));
    u16*   T    = (u16*)(ws + alloc((size_t)4*128*128*256*2));  // [B][W][Hout][C] bf16

    k_detect   <<<1, 256, 0, stream>>>(x, flag);
    k_setup    <<<1, 256, 0, stream>>>(off, dX, dY, d_out, flag);
    k_proj_mfma<<<dim3(5, 512), 256, 0, stream>>>(x, Wq, bq, Wk, bk, Wv, bv, pqk, pvx, flag);
    k_transqk  <<<192, 256, 0, stream>>>(pqk, pkc);
    k_transv   <<<6144, 256, 0, stream>>>(pvx, pvc);
    k_sample   <<<32768, 320, 0, stream>>>(pqk, pvx, dX, dY, qdH, pkc, pvc, qdW, kdW, vdW);
    k_fused    <<<512, 256, 0, stream>>>(pqk, pkc, qdH, qdW, kdW, attbH, attbW);
    k_outcol   <<<512, 256, 0, stream>>>(pvc, attbH, T);
    k_outrow   <<<512, 256, 0, stream>>>(pvx, vdW, attbW, T, x, gamma, d_out, flag);
    (void)in_sizes; (void)n_in; (void)out_size; (void)ws_size;
}